// Round 1
// baseline (358.622 us; speedup 1.0000x reference)
//
#include <hip/hip_runtime.h>

#define NODE_DIM 128
#define OUT_DIM  64
#define NEG_SLOPE 0.01f

// K1: z = h @ W_fc  [N,64]; s_src = z . Wa[:64]; s_dst = z . Wa[64:]
// 4 nodes per 256-thread block; each node owned by one 64-lane wave (lane = out dim).
__global__ __launch_bounds__(256) void k_proj(const float* __restrict__ h,
                                              const float* __restrict__ Wf,
                                              const float* __restrict__ Wa,
                                              float* __restrict__ z,
                                              float* __restrict__ s_src,
                                              float* __restrict__ s_dst,
                                              int N) {
    __shared__ float sWf[NODE_DIM * OUT_DIM];   // 32 KB
    __shared__ float sWa[2 * OUT_DIM];
    __shared__ float sh[4][NODE_DIM];           // 2 KB
    const int t = threadIdx.x;
    for (int i = t; i < NODE_DIM * OUT_DIM; i += 256) sWf[i] = Wf[i];
    if (t < 2 * OUT_DIM) sWa[t] = Wa[t];
    const int node0 = blockIdx.x * 4;
    for (int i = t; i < 4 * NODE_DIM; i += 256) {
        int n = node0 + (i >> 7);
        sh[i >> 7][i & 127] = (n < N) ? h[(size_t)n * NODE_DIM + (i & 127)] : 0.f;
    }
    __syncthreads();
    const int nl = t >> 6;        // node within block: 0..3
    const int d  = t & 63;        // output dim
    const int n  = node0 + nl;
    float acc = 0.f;
    #pragma unroll 8
    for (int k = 0; k < NODE_DIM; ++k)
        acc = fmaf(sh[nl][k], sWf[k * OUT_DIM + d], acc);
    // per-wave (= per-node) reduction for attention logit halves
    float ps = acc * sWa[d];
    float pd = acc * sWa[OUT_DIM + d];
    #pragma unroll
    for (int off = 32; off > 0; off >>= 1) {
        ps += __shfl_down(ps, off, 64);
        pd += __shfl_down(pd, off, 64);
    }
    if (n < N) {
        z[(size_t)n * OUT_DIM + d] = acc;
        if (d == 0) { s_src[n] = ps; s_dst[n] = pd; }
    }
}

// K2: per edge: ex = exp(leaky_relu(s_src[src] + s_dst[dst])); denom[dst] += ex
__global__ __launch_bounds__(256) void k_edge_ex(const int* __restrict__ src,
                                                 const int* __restrict__ dst,
                                                 const float* __restrict__ s_src,
                                                 const float* __restrict__ s_dst,
                                                 float* __restrict__ ex,
                                                 float* __restrict__ denom,
                                                 int E) {
    int i = blockIdx.x * 256 + threadIdx.x;
    if (i >= E) return;
    int s = src[i], d = dst[i];
    float e = s_src[s] + s_dst[d];
    e = (e > 0.f) ? e : e * NEG_SLOPE;
    float x = __expf(e);
    ex[i] = x;
    atomicAdd(denom + d, x);
}

// K3: one wave per edge; lane d: out[dst][d] += (ex/denom[dst]) * z[src][d]
__global__ __launch_bounds__(256) void k_aggregate(const int* __restrict__ src,
                                                   const int* __restrict__ dst,
                                                   const float* __restrict__ ex,
                                                   const float* __restrict__ denom,
                                                   const float* __restrict__ z,
                                                   float* __restrict__ out,
                                                   int E) {
    int eid  = (int)((blockIdx.x * 256u + threadIdx.x) >> 6);
    int lane = threadIdx.x & 63;
    if (eid >= E) return;
    int s = src[eid], d = dst[eid];
    float alpha = ex[eid] / denom[d];
    atomicAdd(out + (size_t)d * OUT_DIM + lane, alpha * z[(size_t)s * OUT_DIM + lane]);
}

extern "C" void kernel_launch(void* const* d_in, const int* in_sizes, int n_in,
                              void* d_out, int out_size, void* d_ws, size_t ws_size,
                              hipStream_t stream) {
    const float* h   = (const float*)d_in[0];
    const int*   src = (const int*)d_in[1];
    const int*   dst = (const int*)d_in[2];
    const float* Wf  = (const float*)d_in[3];
    const float* Wa  = (const float*)d_in[4];
    const int N = in_sizes[0] / NODE_DIM;
    const int E = in_sizes[1];
    float* out = (float*)d_out;

    char* ws = (char*)d_ws;
    float* z     = (float*)ws;                                   // N*64 floats
    float* denom = (float*)(ws + (size_t)N * OUT_DIM * sizeof(float));
    float* s_src = denom + N;
    float* s_dst = s_src + N;
    float* ex    = s_dst + N;                                    // E floats

    hipMemsetAsync(denom, 0, (size_t)N * sizeof(float), stream);
    hipMemsetAsync(out, 0, (size_t)out_size * sizeof(float), stream);

    k_proj<<<(N + 3) / 4, 256, 0, stream>>>(h, Wf, Wa, z, s_src, s_dst, N);
    k_edge_ex<<<(E + 255) / 256, 256, 0, stream>>>(src, dst, s_src, s_dst, ex, denom, E);
    // one wave (64 lanes) per edge
    k_aggregate<<<(int)(((size_t)E * 64 + 255) / 256), 256, 0, stream>>>(src, dst, ex, denom, z, out, E);
}

// Round 2
// 240.045 us; speedup vs baseline: 1.4940x; 1.4940x over previous
//
#include <hip/hip_runtime.h>

#define NODE_DIM 128
#define OUT_DIM  64
#define NEG_SLOPE 0.01f

// ---------------- K1: z = h @ W_fc ; s_src = z.Wa[:64] ; s_dst = z.Wa[64:] ----
// 16 nodes per 256-thread block; each thread computes 4 nodes x 1 dim.
__global__ __launch_bounds__(256) void k_proj(const float* __restrict__ h,
                                              const float* __restrict__ Wf,
                                              const float* __restrict__ Wa,
                                              float* __restrict__ z,
                                              float* __restrict__ s_src,
                                              float* __restrict__ s_dst,
                                              int N) {
    __shared__ float sW[NODE_DIM * OUT_DIM];  // 32 KB, layout [k][d]
    __shared__ float sh[16 * NODE_DIM];       // 8 KB,  layout [node][k]
    const int t = threadIdx.x;
    const int node0 = blockIdx.x * 16;

    // stage W (row-major, same layout as input)
    const float4* Wf4 = (const float4*)Wf;
    float4* sW4 = (float4*)sW;
    #pragma unroll
    for (int i = 0; i < 8; ++i) sW4[t + 256 * i] = Wf4[t + 256 * i];
    // stage 16 node rows of h
    const float4* h4 = (const float4*)(h + (size_t)node0 * NODE_DIM);
    float4* sh4 = (float4*)sh;
    #pragma unroll
    for (int i = 0; i < 2; ++i) {
        int idx = t + 256 * i;                 // < 512 float4s
        if ((size_t)node0 * NODE_DIM + idx * 4 < (size_t)N * NODE_DIM) sh4[idx] = h4[idx];
    }
    __syncthreads();

    const int d = t & 63;
    const int w = t >> 6;                      // wave id: owns nodes w*4..w*4+3
    const float* hp0 = sh + (w * 4 + 0) * NODE_DIM;
    const float* hp1 = sh + (w * 4 + 1) * NODE_DIM;
    const float* hp2 = sh + (w * 4 + 2) * NODE_DIM;
    const float* hp3 = sh + (w * 4 + 3) * NODE_DIM;

    float acc0 = 0.f, acc1 = 0.f, acc2 = 0.f, acc3 = 0.f;
    #pragma unroll
    for (int k = 0; k < NODE_DIM; k += 4) {
        float4 a0 = *(const float4*)(hp0 + k);
        float4 a1 = *(const float4*)(hp1 + k);
        float4 a2 = *(const float4*)(hp2 + k);
        float4 a3 = *(const float4*)(hp3 + k);
        float w0 = sW[(k + 0) * OUT_DIM + d];
        float w1 = sW[(k + 1) * OUT_DIM + d];
        float w2 = sW[(k + 2) * OUT_DIM + d];
        float w3 = sW[(k + 3) * OUT_DIM + d];
        acc0 = fmaf(a0.x, w0, fmaf(a0.y, w1, fmaf(a0.z, w2, fmaf(a0.w, w3, acc0))));
        acc1 = fmaf(a1.x, w0, fmaf(a1.y, w1, fmaf(a1.z, w2, fmaf(a1.w, w3, acc1))));
        acc2 = fmaf(a2.x, w0, fmaf(a2.y, w1, fmaf(a2.z, w2, fmaf(a2.w, w3, acc2))));
        acc3 = fmaf(a3.x, w0, fmaf(a3.y, w1, fmaf(a3.z, w2, fmaf(a3.w, w3, acc3))));
    }

    const float was = Wa[d];
    const float wad = Wa[OUT_DIM + d];
    float ps0 = acc0 * was, pd0 = acc0 * wad;
    float ps1 = acc1 * was, pd1 = acc1 * wad;
    float ps2 = acc2 * was, pd2 = acc2 * wad;
    float ps3 = acc3 * was, pd3 = acc3 * wad;
    #pragma unroll
    for (int off = 32; off > 0; off >>= 1) {
        ps0 += __shfl_down(ps0, off, 64); pd0 += __shfl_down(pd0, off, 64);
        ps1 += __shfl_down(ps1, off, 64); pd1 += __shfl_down(pd1, off, 64);
        ps2 += __shfl_down(ps2, off, 64); pd2 += __shfl_down(pd2, off, 64);
        ps3 += __shfl_down(ps3, off, 64); pd3 += __shfl_down(pd3, off, 64);
    }
    const int n0 = node0 + w * 4;
    if (n0 + 0 < N) z[(size_t)(n0 + 0) * OUT_DIM + d] = acc0;
    if (n0 + 1 < N) z[(size_t)(n0 + 1) * OUT_DIM + d] = acc1;
    if (n0 + 2 < N) z[(size_t)(n0 + 2) * OUT_DIM + d] = acc2;
    if (n0 + 3 < N) z[(size_t)(n0 + 3) * OUT_DIM + d] = acc3;
    if (d == 0) {
        if (n0 + 0 < N) { s_src[n0 + 0] = ps0; s_dst[n0 + 0] = pd0; }
        if (n0 + 1 < N) { s_src[n0 + 1] = ps1; s_dst[n0 + 1] = pd1; }
        if (n0 + 2 < N) { s_src[n0 + 2] = ps2; s_dst[n0 + 2] = pd2; }
        if (n0 + 3 < N) { s_src[n0 + 3] = ps3; s_dst[n0 + 3] = pd3; }
    }
}

// ---------------- K2: degree histogram ----------------
__global__ __launch_bounds__(256) void k_count(const int* __restrict__ dst,
                                               int* __restrict__ deg, int E) {
    int i = blockIdx.x * 256 + threadIdx.x;
    if (i < E) atomicAdd(deg + dst[i], 1);
}

// ---------------- K3a/b/c: exclusive scan of deg -> rstart; cursor=rstart ----
__global__ __launch_bounds__(256) void k_scan_local(const int* __restrict__ deg,
                                                    int* __restrict__ rstart,
                                                    int* __restrict__ bsum, int N) {
    __shared__ int s[256];
    int i = blockIdx.x * 256 + threadIdx.x;
    int t = threadIdx.x;
    int v = (i < N) ? deg[i] : 0;
    s[t] = v;
    __syncthreads();
    #pragma unroll
    for (int off = 1; off < 256; off <<= 1) {
        int u = (t >= off) ? s[t - off] : 0;
        __syncthreads();
        s[t] += u;
        __syncthreads();
    }
    if (i < N) rstart[i] = s[t] - v;       // exclusive
    if (t == 255) bsum[blockIdx.x] = s[255];
}

__global__ __launch_bounds__(256) void k_scan_spine(int* __restrict__ bsum, int nb) {
    __shared__ int s[256];
    int t = threadIdx.x;
    int v = (t < nb) ? bsum[t] : 0;
    s[t] = v;
    __syncthreads();
    #pragma unroll
    for (int off = 1; off < 256; off <<= 1) {
        int u = (t >= off) ? s[t - off] : 0;
        __syncthreads();
        s[t] += u;
        __syncthreads();
    }
    if (t < nb) bsum[t] = s[t] - v;        // exclusive
}

__global__ __launch_bounds__(256) void k_scan_add(int* __restrict__ rstart,
                                                  int* __restrict__ cursor,
                                                  const int* __restrict__ bsum, int N) {
    int i = blockIdx.x * 256 + threadIdx.x;
    if (i < N) {
        int r = rstart[i] + bsum[blockIdx.x];
        rstart[i] = r;
        cursor[i] = r;
    }
}

// ---------------- K4: compute exp(leaky(e)) and scatter (src, ex) into CSR slot
__global__ __launch_bounds__(256) void k_place(const int* __restrict__ src,
                                               const int* __restrict__ dst,
                                               const float* __restrict__ s_src,
                                               const float* __restrict__ s_dst,
                                               int* __restrict__ cursor,
                                               int2* __restrict__ packed, int E) {
    int i = blockIdx.x * 256 + threadIdx.x;
    if (i >= E) return;
    int s = src[i], d = dst[i];
    float e = s_src[s] + s_dst[d];
    e = (e > 0.f) ? e : e * NEG_SLOPE;
    float x = __expf(e);
    int pos = atomicAdd(cursor + d, 1);
    packed[pos] = make_int2(s, __float_as_int(x));
}

// ---------------- K5: per-node aggregation, one wave per dst node -------------
__global__ __launch_bounds__(256) void k_agg(const int* __restrict__ rstart,
                                             const int* __restrict__ deg,
                                             const int2* __restrict__ packed,
                                             const float* __restrict__ z,
                                             float* __restrict__ out, int N) {
    int node = blockIdx.x * 4 + (threadIdx.x >> 6);
    int lane = threadIdx.x & 63;
    if (node >= N) return;
    int rs = rstart[node];
    int dg = deg[node];
    const int2* pk = packed + rs;
    float acc = 0.f, den = 0.f;
    int j = 0;
    for (; j + 1 < dg; j += 2) {
        int2 p0 = pk[j];
        int2 p1 = pk[j + 1];
        float x0 = __int_as_float(p0.y);
        float x1 = __int_as_float(p1.y);
        float z0 = z[(size_t)p0.x * OUT_DIM + lane];
        float z1 = z[(size_t)p1.x * OUT_DIM + lane];
        den += x0 + x1;
        acc = fmaf(x0, z0, fmaf(x1, z1, acc));
    }
    if (j < dg) {
        int2 p0 = pk[j];
        float x0 = __int_as_float(p0.y);
        den += x0;
        acc = fmaf(x0, z[(size_t)p0.x * OUT_DIM + lane], acc);
    }
    out[(size_t)node * OUT_DIM + lane] = (dg > 0) ? acc / den : 0.f;
}

extern "C" void kernel_launch(void* const* d_in, const int* in_sizes, int n_in,
                              void* d_out, int out_size, void* d_ws, size_t ws_size,
                              hipStream_t stream) {
    const float* h   = (const float*)d_in[0];
    const int*   src = (const int*)d_in[1];
    const int*   dst = (const int*)d_in[2];
    const float* Wf  = (const float*)d_in[3];
    const float* Wa  = (const float*)d_in[4];
    const int N = in_sizes[0] / NODE_DIM;
    const int E = in_sizes[1];
    float* out = (float*)d_out;

    char* ws = (char*)d_ws;
    size_t off = 0;
    float* z      = (float*)(ws + off); off += (size_t)N * OUT_DIM * sizeof(float);
    int2*  packed = (int2*)(ws + off);  off += (size_t)E * sizeof(int2);
    int*   deg    = (int*)(ws + off);   off += (size_t)N * sizeof(int);
    int*   rstart = (int*)(ws + off);   off += (size_t)N * sizeof(int);
    int*   cursor = (int*)(ws + off);   off += (size_t)N * sizeof(int);
    float* s_src  = (float*)(ws + off); off += (size_t)N * sizeof(float);
    float* s_dst  = (float*)(ws + off); off += (size_t)N * sizeof(float);
    int*   bsum   = (int*)(ws + off);   off += 256 * sizeof(int);

    const int nbN = (N + 255) / 256;        // 196 for N=50000
    const int nbE = (E + 255) / 256;

    hipMemsetAsync(deg, 0, (size_t)N * sizeof(int), stream);

    k_proj<<<(N + 15) / 16, 256, 0, stream>>>(h, Wf, Wa, z, s_src, s_dst, N);
    k_count<<<nbE, 256, 0, stream>>>(dst, deg, E);
    k_scan_local<<<nbN, 256, 0, stream>>>(deg, rstart, bsum, N);
    k_scan_spine<<<1, 256, 0, stream>>>(bsum, nbN);
    k_scan_add<<<nbN, 256, 0, stream>>>(rstart, cursor, bsum, N);
    k_place<<<nbE, 256, 0, stream>>>(src, dst, s_src, s_dst, cursor, packed, E);
    k_agg<<<(N + 3) / 4, 256, 0, stream>>>(rstart, deg, packed, z, out, N);
}

// Round 3
// 187.058 us; speedup vs baseline: 1.9172x; 1.2833x over previous
//
#include <hip/hip_runtime.h>

#define NODE_DIM 128
#define OUT_DIM  64
#define NEG_SLOPE 0.01f

__device__ __forceinline__ unsigned short f2bf(float f) {
    unsigned u = __float_as_uint(f);
    unsigned r = (u + 0x7FFFu + ((u >> 16) & 1u)) >> 16;
    return (unsigned short)r;
}

// ---- K1 (fused): blocks [0,PB): proj; blocks [PB,PB+CB): degree count + rank
__global__ __launch_bounds__(256) void k_proj_count(const float* __restrict__ h,
                                                    const float* __restrict__ Wf,
                                                    const float* __restrict__ Wa,
                                                    unsigned short* __restrict__ zbf,
                                                    float* __restrict__ s_src,
                                                    float* __restrict__ s_dst,
                                                    const int* __restrict__ dst,
                                                    int* __restrict__ deg,
                                                    int* __restrict__ rank,
                                                    int N, int E, int PB, int CB) {
    if (blockIdx.x >= (unsigned)PB) {
        // ---- count branch: grid-stride over edges ----
        int nthreads = CB * 256;
        for (int i = (blockIdx.x - PB) * 256 + threadIdx.x; i < E; i += nthreads)
            rank[i] = atomicAdd(deg + dst[i], 1);
        return;
    }
    // ---- projection branch: 16 nodes/block, 4 nodes x 1 dim per thread ----
    __shared__ float sW[NODE_DIM * OUT_DIM];  // 32 KB [k][d]
    __shared__ float sh[16 * NODE_DIM];       // 8 KB  [node][k]
    const int t = threadIdx.x;
    const int node0 = blockIdx.x * 16;

    const float4* Wf4 = (const float4*)Wf;
    float4* sW4 = (float4*)sW;
    #pragma unroll
    for (int i = 0; i < 8; ++i) sW4[t + 256 * i] = Wf4[t + 256 * i];
    const float4* h4 = (const float4*)(h + (size_t)node0 * NODE_DIM);
    float4* sh4 = (float4*)sh;
    #pragma unroll
    for (int i = 0; i < 2; ++i) {
        int idx = t + 256 * i;
        if ((size_t)node0 * NODE_DIM + idx * 4 < (size_t)N * NODE_DIM) sh4[idx] = h4[idx];
    }
    __syncthreads();

    const int d = t & 63;
    const int w = t >> 6;
    const float* hp0 = sh + (w * 4 + 0) * NODE_DIM;
    const float* hp1 = sh + (w * 4 + 1) * NODE_DIM;
    const float* hp2 = sh + (w * 4 + 2) * NODE_DIM;
    const float* hp3 = sh + (w * 4 + 3) * NODE_DIM;

    float acc0 = 0.f, acc1 = 0.f, acc2 = 0.f, acc3 = 0.f;
    #pragma unroll
    for (int k = 0; k < NODE_DIM; k += 4) {
        float4 a0 = *(const float4*)(hp0 + k);
        float4 a1 = *(const float4*)(hp1 + k);
        float4 a2 = *(const float4*)(hp2 + k);
        float4 a3 = *(const float4*)(hp3 + k);
        float w0 = sW[(k + 0) * OUT_DIM + d];
        float w1 = sW[(k + 1) * OUT_DIM + d];
        float w2 = sW[(k + 2) * OUT_DIM + d];
        float w3 = sW[(k + 3) * OUT_DIM + d];
        acc0 = fmaf(a0.x, w0, fmaf(a0.y, w1, fmaf(a0.z, w2, fmaf(a0.w, w3, acc0))));
        acc1 = fmaf(a1.x, w0, fmaf(a1.y, w1, fmaf(a1.z, w2, fmaf(a1.w, w3, acc1))));
        acc2 = fmaf(a2.x, w0, fmaf(a2.y, w1, fmaf(a2.z, w2, fmaf(a2.w, w3, acc2))));
        acc3 = fmaf(a3.x, w0, fmaf(a3.y, w1, fmaf(a3.z, w2, fmaf(a3.w, w3, acc3))));
    }

    const float was = Wa[d];
    const float wad = Wa[OUT_DIM + d];
    float ps0 = acc0 * was, pd0 = acc0 * wad;
    float ps1 = acc1 * was, pd1 = acc1 * wad;
    float ps2 = acc2 * was, pd2 = acc2 * wad;
    float ps3 = acc3 * was, pd3 = acc3 * wad;
    #pragma unroll
    for (int off = 32; off > 0; off >>= 1) {
        ps0 += __shfl_down(ps0, off, 64); pd0 += __shfl_down(pd0, off, 64);
        ps1 += __shfl_down(ps1, off, 64); pd1 += __shfl_down(pd1, off, 64);
        ps2 += __shfl_down(ps2, off, 64); pd2 += __shfl_down(pd2, off, 64);
        ps3 += __shfl_down(ps3, off, 64); pd3 += __shfl_down(pd3, off, 64);
    }
    const int n0 = node0 + w * 4;
    if (n0 + 0 < N) zbf[(size_t)(n0 + 0) * OUT_DIM + d] = f2bf(acc0);
    if (n0 + 1 < N) zbf[(size_t)(n0 + 1) * OUT_DIM + d] = f2bf(acc1);
    if (n0 + 2 < N) zbf[(size_t)(n0 + 2) * OUT_DIM + d] = f2bf(acc2);
    if (n0 + 3 < N) zbf[(size_t)(n0 + 3) * OUT_DIM + d] = f2bf(acc3);
    if (d == 0) {
        if (n0 + 0 < N) { s_src[n0 + 0] = ps0; s_dst[n0 + 0] = pd0; }
        if (n0 + 1 < N) { s_src[n0 + 1] = ps1; s_dst[n0 + 1] = pd1; }
        if (n0 + 2 < N) { s_src[n0 + 2] = ps2; s_dst[n0 + 2] = pd2; }
        if (n0 + 3 < N) { s_src[n0 + 3] = ps3; s_dst[n0 + 3] = pd3; }
    }
}

// ---- K2: per-block exclusive scan of deg -> rstart(local); bsum[b] = total
__global__ __launch_bounds__(256) void k_scan_local(const int* __restrict__ deg,
                                                    int* __restrict__ rstart,
                                                    int* __restrict__ bsum, int N) {
    __shared__ int s[256];
    int i = blockIdx.x * 256 + threadIdx.x;
    int t = threadIdx.x;
    int v = (i < N) ? deg[i] : 0;
    s[t] = v;
    __syncthreads();
    #pragma unroll
    for (int off = 1; off < 256; off <<= 1) {
        int u = (t >= off) ? s[t - off] : 0;
        __syncthreads();
        s[t] += u;
        __syncthreads();
    }
    if (i < N) rstart[i] = s[t] - v;
    if (t == 255) bsum[blockIdx.x] = s[255];
}

// ---- K3: every block redundantly scans the spine, adds its offset
__global__ __launch_bounds__(256) void k_scan_add(int* __restrict__ rstart,
                                                  const int* __restrict__ bsum,
                                                  int N, int nb) {
    __shared__ int s[256];
    int t = threadIdx.x;
    s[t] = (t < nb) ? bsum[t] : 0;
    __syncthreads();
    #pragma unroll
    for (int off = 1; off < 256; off <<= 1) {
        int u = (t >= off) ? s[t - off] : 0;
        __syncthreads();
        s[t] += u;
        __syncthreads();
    }
    int boff = (blockIdx.x > 0) ? s[blockIdx.x - 1] : 0;   // inclusive scan -> exclusive offset
    int i = blockIdx.x * 256 + t;
    if (i < N) rstart[i] += boff;
}

// ---- K4: place (src, exp(leaky(e))) at rstart[dst] + rank  — no atomics
__global__ __launch_bounds__(256) void k_place(const int* __restrict__ src,
                                               const int* __restrict__ dst,
                                               const int* __restrict__ rank,
                                               const int* __restrict__ rstart,
                                               const float* __restrict__ s_src,
                                               const float* __restrict__ s_dst,
                                               int2* __restrict__ packed, int E) {
    int i = blockIdx.x * 256 + threadIdx.x;
    if (i >= E) return;
    int s = src[i], d = dst[i];
    float e = s_src[s] + s_dst[d];
    e = (e > 0.f) ? e : e * NEG_SLOPE;
    float x = __expf(e);
    int pos = rstart[d] + rank[i];
    packed[pos] = make_int2(s, __float_as_int(x));
}

// ---- K5: one wave per dst node; lane-parallel packed load + shfl broadcast
__global__ __launch_bounds__(256) void k_agg(const int* __restrict__ rstart,
                                             const int* __restrict__ deg,
                                             const int2* __restrict__ packed,
                                             const unsigned short* __restrict__ zbf,
                                             float* __restrict__ out, int N) {
    int node = blockIdx.x * 4 + (threadIdx.x >> 6);
    int lane = threadIdx.x & 63;
    if (node >= N) return;
    int rs = rstart[node];
    int dg = deg[node];
    const int2* pk = packed + rs;
    float acc = 0.f, den = 0.f;
    for (int base = 0; base < dg; base += 64) {
        int m = dg - base; if (m > 64) m = 64;
        int2 p = make_int2(0, 0);
        if (lane < m) p = pk[base + lane];
        float xl = __int_as_float(p.y);
        den += xl;                                    // lane-partial denom
        int j = 0;
        for (; j + 3 < m; j += 4) {
            int s0 = __shfl(p.x, j + 0, 64); float x0 = __shfl(xl, j + 0, 64);
            int s1 = __shfl(p.x, j + 1, 64); float x1 = __shfl(xl, j + 1, 64);
            int s2 = __shfl(p.x, j + 2, 64); float x2 = __shfl(xl, j + 2, 64);
            int s3 = __shfl(p.x, j + 3, 64); float x3 = __shfl(xl, j + 3, 64);
            float z0 = __uint_as_float((unsigned)zbf[(size_t)s0 * OUT_DIM + lane] << 16);
            float z1 = __uint_as_float((unsigned)zbf[(size_t)s1 * OUT_DIM + lane] << 16);
            float z2 = __uint_as_float((unsigned)zbf[(size_t)s2 * OUT_DIM + lane] << 16);
            float z3 = __uint_as_float((unsigned)zbf[(size_t)s3 * OUT_DIM + lane] << 16);
            acc = fmaf(x0, z0, fmaf(x1, z1, fmaf(x2, z2, fmaf(x3, z3, acc))));
        }
        for (; j < m; ++j) {
            int s0 = __shfl(p.x, j, 64); float x0 = __shfl(xl, j, 64);
            acc = fmaf(x0, __uint_as_float((unsigned)zbf[(size_t)s0 * OUT_DIM + lane] << 16), acc);
        }
    }
    #pragma unroll
    for (int off = 32; off > 0; off >>= 1) den += __shfl_xor(den, off, 64);
    out[(size_t)node * OUT_DIM + lane] = (dg > 0) ? acc / den : 0.f;
}

extern "C" void kernel_launch(void* const* d_in, const int* in_sizes, int n_in,
                              void* d_out, int out_size, void* d_ws, size_t ws_size,
                              hipStream_t stream) {
    const float* h   = (const float*)d_in[0];
    const int*   src = (const int*)d_in[1];
    const int*   dst = (const int*)d_in[2];
    const float* Wf  = (const float*)d_in[3];
    const float* Wa  = (const float*)d_in[4];
    const int N = in_sizes[0] / NODE_DIM;
    const int E = in_sizes[1];
    float* out = (float*)d_out;

    char* ws = (char*)d_ws;
    size_t off = 0;
    unsigned short* zbf = (unsigned short*)(ws + off); off += (size_t)N * OUT_DIM * sizeof(unsigned short);
    int2*  packed = (int2*)(ws + off);  off += (size_t)E * sizeof(int2);
    int*   rank   = (int*)(ws + off);   off += (size_t)E * sizeof(int);
    int*   deg    = (int*)(ws + off);   off += (size_t)N * sizeof(int);
    int*   rstart = (int*)(ws + off);   off += (size_t)N * sizeof(int);
    float* s_src  = (float*)(ws + off); off += (size_t)N * sizeof(float);
    float* s_dst  = (float*)(ws + off); off += (size_t)N * sizeof(float);
    int*   bsum   = (int*)(ws + off);   off += 256 * sizeof(int);

    const int PB = (N + 15) / 16;            // proj blocks (3125)
    const int CB = 1024;                     // count blocks (grid-stride)
    const int nbN = (N + 255) / 256;         // 196
    const int nbE = (E + 255) / 256;

    hipMemsetAsync(deg, 0, (size_t)N * sizeof(int), stream);

    k_proj_count<<<PB + CB, 256, 0, stream>>>(h, Wf, Wa, zbf, s_src, s_dst,
                                              dst, deg, rank, N, E, PB, CB);
    k_scan_local<<<nbN, 256, 0, stream>>>(deg, rstart, bsum, N);
    k_scan_add<<<nbN, 256, 0, stream>>>(rstart, bsum, N, nbN);
    k_place<<<nbE, 256, 0, stream>>>(src, dst, rank, rstart, s_src, s_dst, packed, E);
    k_agg<<<(N + 3) / 4, 256, 0, stream>>>(rstart, deg, packed, zbf, out, N);
}